// Round 1
// baseline (244.505 us; speedup 1.0000x reference)
//
#include <hip/hip_runtime.h>
#include <math.h>

// Problem constants
constexpr int kT = 512;
constexpr int kB = 8;
constexpr int kD = 512;
constexpr int kM = 128;
constexpr int kNPairs = kT * kB;        // 4096 independent (t,b) pairs
constexpr int kGP = 8;                  // pairs per block
constexpr int kThreads = 256;

__global__ __launch_bounds__(kThreads)
void mlstm_fused(const float* __restrict__ x,
                 const float* __restrict__ C_prev,
                 const float* __restrict__ n_prev,
                 const float* __restrict__ Wq, const float* __restrict__ bq,
                 const float* __restrict__ Wk, const float* __restrict__ bk,
                 const float* __restrict__ Wv, const float* __restrict__ bv,
                 const float* __restrict__ wi, const float* __restrict__ bi,
                 const float* __restrict__ wf, const float* __restrict__ bf,
                 const float* __restrict__ Wo, const float* __restrict__ bo,
                 float* __restrict__ out_ht,
                 float* __restrict__ out_C,
                 float* __restrict__ out_n)
{
    __shared__ float sx[kGP][kD];     // 16 KB staged x
    __shared__ float sq[kGP][kM];     // 4 KB
    __shared__ float sk[kGP][kM];     // 4 KB (already scaled by 1/sqrt(M))
    __shared__ float sv[kGP][kM];     // 4 KB
    __shared__ float so[kGP][kM];     // 4 KB (sigmoid applied)
    __shared__ float sh[kGP][kM];     // 4 KB (h accumulators)
    __shared__ float sif[kGP][2];     // i, f per pair

    const int tid = threadIdx.x;
    const int pair_base = blockIdx.x * kGP;

    // ---------------- phase 0: stage x for 8 pairs (coalesced float4) -------
    {
        const float4* xg = reinterpret_cast<const float4*>(x + (size_t)pair_base * kD);
        float4* sxf = reinterpret_cast<float4*>(&sx[0][0]);
        #pragma unroll
        for (int u = 0; u < (kGP * kD / 4) / kThreads; ++u) {
            sxf[tid + kThreads * u] = xg[tid + kThreads * u];
        }
    }
    __syncthreads();

    // ---------------- phase 1: gates q,k,v,o (float4 cols) + i,f ------------
    {
        const int w  = tid >> 6;        // wave 0..3
        const int l  = tid & 63;
        const int hh = l >> 5;          // half of wave
        const int p  = 2 * w + hh;      // pair 0..7
        const int s  = l & 31;
        const int c  = s * 4;           // column base (0..124)

        float4 aq = {0.f,0.f,0.f,0.f};
        float4 ak = {0.f,0.f,0.f,0.f};
        float4 av = {0.f,0.f,0.f,0.f};
        float4 ao = {0.f,0.f,0.f,0.f};

        #pragma unroll 4
        for (int d = 0; d < kD; ++d) {
            const float xv = sx[p][d];
            const float4 wq4 = *reinterpret_cast<const float4*>(Wq + d * kM + c);
            const float4 wk4 = *reinterpret_cast<const float4*>(Wk + d * kM + c);
            const float4 wv4 = *reinterpret_cast<const float4*>(Wv + d * kM + c);
            const float4 wo4 = *reinterpret_cast<const float4*>(Wo + d * kM + c);
            aq.x += xv * wq4.x; aq.y += xv * wq4.y; aq.z += xv * wq4.z; aq.w += xv * wq4.w;
            ak.x += xv * wk4.x; ak.y += xv * wk4.y; ak.z += xv * wk4.z; ak.w += xv * wk4.w;
            av.x += xv * wv4.x; av.y += xv * wv4.y; av.z += xv * wv4.z; av.w += xv * wv4.w;
            ao.x += xv * wo4.x; ao.y += xv * wo4.y; ao.z += xv * wo4.z; ao.w += xv * wo4.w;
        }

        // i/f dot partials: lane s covers d = s, s+32, ...
        float ip = 0.f, fp = 0.f;
        #pragma unroll
        for (int dd = 0; dd < kD / 32; ++dd) {
            const int d = s + 32 * dd;
            const float xv = sx[p][d];
            ip += xv * wi[d];
            fp += xv * wf[d];
        }
        #pragma unroll
        for (int msk = 16; msk >= 1; msk >>= 1) {
            ip += __shfl_xor(ip, msk, 64);
            fp += __shfl_xor(fp, msk, 64);
        }
        const float i_val = expf(ip + bi[0]);
        const float f_val = 1.f / (1.f + expf(-(fp + bf[0])));
        if (s == 0) { sif[p][0] = i_val; sif[p][1] = f_val; }

        const float inv_sqrt_m = 0.08838834764831845f;  // 1/sqrt(128)
        const float4 bq4 = *reinterpret_cast<const float4*>(bq + c);
        const float4 bk4 = *reinterpret_cast<const float4*>(bk + c);
        const float4 bv4 = *reinterpret_cast<const float4*>(bv + c);
        const float4 bo4 = *reinterpret_cast<const float4*>(bo + c);

        float4 qv, kv, vv, ov;
        qv.x = aq.x + bq4.x; qv.y = aq.y + bq4.y; qv.z = aq.z + bq4.z; qv.w = aq.w + bq4.w;
        kv.x = (ak.x + bk4.x) * inv_sqrt_m; kv.y = (ak.y + bk4.y) * inv_sqrt_m;
        kv.z = (ak.z + bk4.z) * inv_sqrt_m; kv.w = (ak.w + bk4.w) * inv_sqrt_m;
        vv.x = av.x + bv4.x; vv.y = av.y + bv4.y; vv.z = av.z + bv4.z; vv.w = av.w + bv4.w;
        ov.x = 1.f / (1.f + expf(-(ao.x + bo4.x)));
        ov.y = 1.f / (1.f + expf(-(ao.y + bo4.y)));
        ov.z = 1.f / (1.f + expf(-(ao.z + bo4.z)));
        ov.w = 1.f / (1.f + expf(-(ao.w + bo4.w)));

        *reinterpret_cast<float4*>(&sq[p][c]) = qv;
        *reinterpret_cast<float4*>(&sk[p][c]) = kv;
        *reinterpret_cast<float4*>(&sv[p][c]) = vv;
        *reinterpret_cast<float4*>(&so[p][c]) = ov;
    }
    __syncthreads();

    // ---------------- phase 2: stream C (read once, write once, fuse C.q) ---
    {
        const int r0 = tid >> 5;        // 0..7
        const int s  = tid & 31;        // col group; cols 4s..4s+3

        for (int p = 0; p < kGP; ++p) {
            const size_t cbase = (size_t)(pair_base + p) * (kM * kM);
            const float4* cp = reinterpret_cast<const float4*>(C_prev + cbase);
            float4*       cn = reinterpret_cast<float4*>(out_C + cbase);
            const float iv = sif[p][0];
            const float fv = sif[p][1];
            const float4 k4 = *reinterpret_cast<const float4*>(&sk[p][4 * s]);
            const float4 q4 = *reinterpret_cast<const float4*>(&sq[p][4 * s]);

            float hpart[16];
            #pragma unroll
            for (int j = 0; j < 16; ++j) {
                const int fi = tid + kThreads * j;   // float4 flat index
                const int r  = r0 + 8 * j;           // row of this float4
                const float  vr  = sv[p][r];
                const float4 cp4 = cp[fi];
                const float  ivr = iv * vr;
                float4 c_new;
                c_new.x = fv * cp4.x + ivr * k4.x;
                c_new.y = fv * cp4.y + ivr * k4.y;
                c_new.z = fv * cp4.z + ivr * k4.z;
                c_new.w = fv * cp4.w + ivr * k4.w;
                cn[fi] = c_new;
                hpart[j] = c_new.x * q4.x + c_new.y * q4.y
                         + c_new.z * q4.z + c_new.w * q4.w;
            }
            #pragma unroll
            for (int j = 0; j < 16; ++j) {
                float v = hpart[j];
                v += __shfl_xor(v, 16, 64);
                v += __shfl_xor(v, 8, 64);
                v += __shfl_xor(v, 4, 64);
                v += __shfl_xor(v, 2, 64);
                v += __shfl_xor(v, 1, 64);
                if (s == 0) sh[p][r0 + 8 * j] = v;
            }
        }
    }
    __syncthreads();

    // ---------------- phase 3: n update, normalizer, ht ---------------------
    {
        const int p = tid >> 5;         // pair 0..7 (32 threads per pair)
        const int s = tid & 31;
        const size_t pi = (size_t)(pair_base + p);
        const float iv = sif[p][0];
        const float fv = sif[p][1];

        const float4 np4 = *reinterpret_cast<const float4*>(n_prev + pi * kM + 4 * s);
        const float4 k4  = *reinterpret_cast<const float4*>(&sk[p][4 * s]);
        const float4 q4  = *reinterpret_cast<const float4*>(&sq[p][4 * s]);

        float4 n4;
        n4.x = fv * np4.x + iv * k4.x;
        n4.y = fv * np4.y + iv * k4.y;
        n4.z = fv * np4.z + iv * k4.z;
        n4.w = fv * np4.w + iv * k4.w;
        *reinterpret_cast<float4*>(out_n + pi * kM + 4 * s) = n4;

        float nq = n4.x * q4.x + n4.y * q4.y + n4.z * q4.z + n4.w * q4.w;
        nq += __shfl_xor(nq, 16, 64);
        nq += __shfl_xor(nq, 8, 64);
        nq += __shfl_xor(nq, 4, 64);
        nq += __shfl_xor(nq, 2, 64);
        nq += __shfl_xor(nq, 1, 64);
        const float inv = 1.f / fmaxf(fabsf(nq), 1.0f);

        const float4 h4 = *reinterpret_cast<const float4*>(&sh[p][4 * s]);
        const float4 o4 = *reinterpret_cast<const float4*>(&so[p][4 * s]);
        float4 ht4;
        ht4.x = o4.x * h4.x * inv;
        ht4.y = o4.y * h4.y * inv;
        ht4.z = o4.z * h4.z * inv;
        ht4.w = o4.w * h4.w * inv;
        *reinterpret_cast<float4*>(out_ht + pi * kM + 4 * s) = ht4;
    }
}

extern "C" void kernel_launch(void* const* d_in, const int* in_sizes, int n_in,
                              void* d_out, int out_size, void* d_ws, size_t ws_size,
                              hipStream_t stream) {
    const float* x      = (const float*)d_in[0];
    const float* C_prev = (const float*)d_in[1];
    const float* n_prev = (const float*)d_in[2];
    const float* Wq = (const float*)d_in[3];
    const float* bq = (const float*)d_in[4];
    const float* Wk = (const float*)d_in[5];
    const float* bk = (const float*)d_in[6];
    const float* Wv = (const float*)d_in[7];
    const float* bv = (const float*)d_in[8];
    const float* wi = (const float*)d_in[9];
    const float* bi = (const float*)d_in[10];
    const float* wf = (const float*)d_in[11];
    const float* bf = (const float*)d_in[12];
    const float* Wo = (const float*)d_in[13];
    const float* bo = (const float*)d_in[14];

    float* out    = (float*)d_out;
    float* out_ht = out;                                    // (T,B,M)
    float* out_C  = out + (size_t)kNPairs * kM;             // (T,B,M,M)
    float* out_n  = out_C + (size_t)kNPairs * kM * kM;      // (T,B,M)

    dim3 grid(kNPairs / kGP);
    dim3 block(kThreads);
    mlstm_fused<<<grid, block, 0, stream>>>(x, C_prev, n_prev,
                                            Wq, bq, Wk, bk, Wv, bv,
                                            wi, bi, wf, bf, Wo, bo,
                                            out_ht, out_C, out_n);
}